// Round 7
// baseline (463.898 us; speedup 1.0000x reference)
//
#include <hip/hip_runtime.h>
#include <cstdint>
#include <cstddef>

// ---------------------------------------------------------------------------
// feature_matching: corr(P=20, C=64) -> 4x (depthwise 3^3 + pointwise) blocks
//
// R7 = R6 with the LDS swizzle bug fixed: the (h&4)?14:0 offset overflowed
// the CINP slot (12 half-words spilled into the next position's region ->
// write-write race at run boundaries -> absmax 7e-6). CINP odd-dword stride
// (22/42) alone kills the bank conflicts; 2-way hh2 aliasing is free.
//  - corr v3: block=(di-group of 4, h, b); A-frags reused over 4 di; no
//    __syncthreads (wave-private Dall slices).
//  - fused_block v6: 8-wide w-groups, interior fast path, HT=8 for b1.
//    Phase 2 = f16 MFMA (M=16 w, N=16 co, K=32 ci).
//
// ws layout (peak 157,286,400 B):
//   [0,        78.6MB): corrO (f16)        -> later b2o (f16, 19.7MB)
//   [78.6MB,  157.3MB): rgbT+depT (f16)    -> later b1o (f16, 78.6MB)
//                                          -> later b3o (f16, 19.7MB)
// ---------------------------------------------------------------------------

typedef unsigned short u16;
typedef _Float16 f16_t;
typedef __attribute__((ext_vector_type(2))) _Float16 half2_t;
typedef __attribute__((ext_vector_type(8))) _Float16 half8_t;
typedef __attribute__((ext_vector_type(4))) float f32x4;

static __device__ inline u16 f2h(float f) {
    union { f16_t h; u16 u; } v; v.h = (f16_t)f; return v.u;
}
static __device__ inline half2_t H2(uint32_t u) {
    union { uint32_t u; half2_t h; } v; v.u = u; return v.h;
}

#if __has_builtin(__builtin_amdgcn_fdot2)
static __device__ inline float FDOT2(half2_t a, half2_t b, float c) {
    return __builtin_amdgcn_fdot2(a, b, c, false);
}
#else
static __device__ inline float FDOT2(half2_t a, half2_t b, float c) {
    return fmaf((float)a.x, (float)b.x, fmaf((float)a.y, (float)b.y, c));
}
#endif

#if __has_builtin(__builtin_amdgcn_alignbit)
static __device__ inline uint32_t mkp(uint32_t lo, uint32_t hi) {
    return __builtin_amdgcn_alignbit(hi, lo, 16);   // (lo.hi16, hi.lo16)
}
#else
static __device__ inline uint32_t mkp(uint32_t lo, uint32_t hi) {
    return (lo >> 16) | (hi << 16);
}
#endif

static __device__ inline uint32_t ldu(const u16* p) { return *(const uint32_t*)p; }

// ---------------------------------------------------------------------------
// Prepass: (b,c,h,w) fp32 -> (b,h,w,c) f16, LDS tile transpose per (b,h).
// ---------------------------------------------------------------------------
__global__ __launch_bounds__(256) void transpose_f16(
        const float* __restrict__ rgb, const float* __restrict__ dep,
        u16* __restrict__ rgbT, u16* __restrict__ depT) {
    const int bh = blockIdx.x;
    const float* src = blockIdx.y ? dep : rgb;
    u16* dst = blockIdx.y ? depT : rgbT;
    const int tid = threadIdx.x;
    const int b = bh >> 6, h = bh & 63;

    __shared__ u16 S[64 * 194];

    const float* srcb = src + (size_t)b * 786432 + (size_t)h * 192;
#pragma unroll
    for (int it = 0; it < 12; ++it) {
        const int idx = it * 256 + tid;      // 3072 = 64c x 48 float4
        const int c = idx / 48, w4 = idx - c * 48;
        const float4 v = *(const float4*)(srcb + (size_t)c * 12288 + 4 * w4);
        u16* sp = &S[c * 194 + 4 * w4];
        sp[0] = f2h(v.x); sp[1] = f2h(v.y); sp[2] = f2h(v.z); sp[3] = f2h(v.w);
    }
    __syncthreads();
    u16* dstb = dst + (size_t)bh * 192 * 64;
#pragma unroll
    for (int it = 0; it < 12; ++it) {
        const int idx = it * 256 + tid;      // 3072 = 192w x 16 c4
        const int w = idx >> 4, c4 = idx & 15;
        ushort4 o;
        o.x = S[(4 * c4 + 0) * 194 + w];
        o.y = S[(4 * c4 + 1) * 194 + w];
        o.z = S[(4 * c4 + 2) * 194 + w];
        o.w = S[(4 * c4 + 3) * 194 + w];
        *(ushort4*)(dstb + (size_t)w * 64 + 4 * c4) = o;
    }
}

// ---------------------------------------------------------------------------
// corr v3. Grid (dig=5, h=64, b=8), 256 threads (4 waves, no barriers).
// Wave owns 48 w; A-frags (rgb row) loaded once, reused over 4 di.
// Per di: banded Z via f16 MFMA, scatter to the wave's PRIVATE Dall slice
// in (w,dj) coords, wave-local readout (no cross-wave data).
// ---------------------------------------------------------------------------
__global__ __launch_bounds__(256) void corr_mfma(
        const u16* __restrict__ rgbT, const u16* __restrict__ depT,
        u16* __restrict__ out) {
    const int dig = blockIdx.x, h = blockIdx.y, b = blockIdx.z;
    const int tid = threadIdx.x;
    const int lane = tid & 63, wave = tid >> 6;
    const int n = lane & 15, q = lane >> 4;

    __shared__ float Dall[4080];         // addr = w*21 + (w>>2) + dj

    const u16* Abase = rgbT + (size_t)(b * 64 + h) * 12288;
    half8_t a0[3], a1[3];
#pragma unroll
    for (int t = 0; t < 3; ++t) {
        const int w0 = wave * 48 + t * 16;
        const half8_t* Ap = (const half8_t*)(Abase + (size_t)(w0 + n) * 64 + q * 8);
        a0[t] = Ap[0];                   // c = q*8 .. q*8+7
        a1[t] = Ap[4];                   // c += 32
    }

#pragma unroll
    for (int i = 0; i < 4; ++i) {
        const int di = dig * 4 + i;
        const int hd = h + di - 10;
        u16* outb = out + ((size_t)((b * 20 + di) * 20) * 64 + h) * 192;

        if (hd < 0 || hd >= 64) {        // depth row fully in zero-pad
#pragma unroll
            for (int it = 0; it < 4; ++it) {
                const int item = it * 64 + lane;
                if (item < 240) {
                    const int dj = item / 12;
                    const int w4 = wave * 12 + (item - dj * 12);
                    *(ushort4*)(outb + (size_t)dj * 12288 + 4 * w4) =
                        make_ushort4(0, 0, 0, 0);
                }
            }
            continue;
        }

        const u16* Bbase = depT + (size_t)(b * 64 + hd) * 12288;
#pragma unroll
        for (int t = 0; t < 3; ++t) {
            const int w0 = wave * 48 + t * 16;
            f32x4 acc[3];
#pragma unroll
            for (int ut = 0; ut < 3; ++ut) {
                acc[ut].x = 0.f; acc[ut].y = 0.f; acc[ut].z = 0.f; acc[ut].w = 0.f;
            }
#pragma unroll
            for (int ut = 0; ut < 3; ++ut) {
                const int u0 = w0 + (ut - 1) * 16;
                if (u0 >= 0 && u0 <= 176) {  // wave-uniform; OOB tile stays 0
                    const half8_t* Bp = (const half8_t*)(Bbase + (size_t)(u0 + n) * 64 + q * 8);
                    acc[ut] = __builtin_amdgcn_mfma_f32_16x16x32_f16(a0[t], Bp[0], acc[ut], 0, 0, 0);
                    acc[ut] = __builtin_amdgcn_mfma_f32_16x16x32_f16(a1[t], Bp[4], acc[ut], 0, 0, 0);
                }
            }
#pragma unroll
            for (int ut = 0; ut < 3; ++ut) {
#pragma unroll
                for (int r = 0; r < 4; ++r) {
                    const int dj = 16 * ut + n - 4 * q - r - 6;
                    const int w = w0 + 4 * q + r;
                    if (dj >= 0 && dj < 20)
                        Dall[w * 21 + (w >> 2) + dj] = acc[ut][r];
                }
            }
        }
        // wave-local readout (writes above are by this wave only)
#pragma unroll
        for (int it = 0; it < 4; ++it) {
            const int item = it * 64 + lane;
            if (item < 240) {
                const int dj = item / 12;
                const int w4 = wave * 12 + (item - dj * 12);
                const int base = 85 * w4 + dj;   // (4*w4+j)*21 + w4 + dj
                ushort4 o;
                o.x = f2h(Dall[base]);
                o.y = f2h(Dall[base + 21]);
                o.z = f2h(Dall[base + 42]);
                o.w = f2h(Dall[base + 63]);
                *(ushort4*)(outb + (size_t)dj * 12288 + 4 * w4) = o;
            }
        }
    }
}

// ---------------------------------------------------------------------------
// Fused block v6b. Tile: DT d x HT h x 48 w. Phase 1 task = (ci, wg, hh2):
// W8 outputs wide, 4 h, DT d. Interior blocks take a guard-free unrolled
// path. dw out (bias+leaky, f16) -> LDS sT[pos][ci], stride CINP with odd
// dword count (22/42) -> conflict-light ds (2-way aliasing is free).
// NO extra swizzle offset (R6's overflowed the slot -> race).
// Phase 2 = f16 MFMA (M=16 w, N=16 co, K=32 ci).
// ---------------------------------------------------------------------------
template<int CIN, int COUT, int S, int DT, int HT, int DIN, int HIN, int WIN,
         int DO, int HO, int WO, typename TOUT>
__global__ __launch_bounds__(256) void fused_block(
        const u16* __restrict__ x,
        const float* __restrict__ dw_w, const float* __restrict__ dw_b,
        const float* __restrict__ pw_w, const float* __restrict__ pw_b,
        TOUT* __restrict__ y) {
    static_assert(WO % 48 == 0 && HO % HT == 0 && (HT == 4 || HT == 8), "tile");
    constexpr int CINP = (CIN == 20) ? 22 : 42;    // odd dword stride
    constexpr int HH = HT / 4;
    constexpr int W8 = (CIN * 6 * HH >= 240) ? 8 : 4;
    constexpr int SUB = (48 / W8) * HH;            // tasks per ci
    constexpr int NTASK = CIN * SUB;
    constexpr int WT = WO / 48;
    constexpr int NP = S * (DT - 1) + 3;
    static_assert(W8 == 8 || S == 2, "W4 path implemented for S=2 only");

    const int wt = blockIdx.x % WT;
    const int ht = blockIdx.x / WT;
    const int d0 = blockIdx.y * DT;
    const int b  = blockIdx.z;
    const int tid = threadIdx.x;
    const int h0 = ht * HT;
    const int wbase = wt * 48;

    __shared__ float sDW[CIN * 27];
    __shared__ float sDB[CIN];
    __shared__ u16   sT[DT * HT * 48 * CINP + 16];

    for (int i = tid; i < CIN * 27; i += 256) sDW[i] = dw_w[i];
    for (int i = tid; i < CIN; i += 256) sDB[i] = dw_b[i];
    __syncthreads();

    // ---------------- phase 1: depthwise via fdot2 ----------------
    for (int idx = tid; idx < NTASK; idx += 256) {
        const int ci = idx / SUB;
        const int rem = idx - ci * SUB;
        const int wg = rem / HH;
        const int hh2 = rem - wg * HH;
        const int w0g = wbase + wg * W8;
        const int h0t = h0 + hh2 * 4;

        half2_t KA[9], KB[9];
#pragma unroll
        for (int t = 0; t < 9; ++t) {
            const int kd = t / 3, kh = t - 3 * kd;
            const float k0 = sDW[ci * 27 + kd * 9 + kh * 3 + 0];
            const float k1 = sDW[ci * 27 + kd * 9 + kh * 3 + 1];
            const float k2 = sDW[ci * 27 + kd * 9 + kh * 3 + 2];
            half2_t a; a.x = (f16_t)k0; a.y = (f16_t)k1; KA[t] = a;
            half2_t bb;
            if constexpr (S == 1) { bb.x = (f16_t)k2; bb.y = (f16_t)0.f; }
            else                  { bb.x = (f16_t)0.f; bb.y = (f16_t)k2; }
            KB[t] = bb;
        }

        float acc[DT][4][W8];
#pragma unroll
        for (int dl = 0; dl < DT; ++dl)
#pragma unroll
            for (int a = 0; a < 4; ++a)
#pragma unroll
                for (int c = 0; c < W8; ++c) acc[dl][a][c] = 0.f;

        const u16* plane0 = x + (size_t)(b * CIN + ci) * DIN * HIN * WIN;

        auto row_body = [&](int p, int r, const u16* pl) {
            const int hin = h0t * S - 1 + r;
            const u16* rowp = pl + (size_t)hin * WIN + (size_t)w0g * S;
            uint32_t PA[W8], PB[W8];
            if constexpr (W8 == 8) {
                if constexpr (S == 1) {
                    const uint32_t Wm = (w0g > 0) ? ldu(rowp - 2) : 0u;
                    const uint4 X = *(const uint4*)rowp;            // x0..x7
                    const uint32_t Wp = (w0g + 8 < WIN) ? ldu(rowp + 8) : 0u;
                    const uint32_t mm0 = mkp(Wm, X.x);
                    const uint32_t m01 = mkp(X.x, X.y);
                    const uint32_t m12 = mkp(X.y, X.z);
                    const uint32_t m23 = mkp(X.z, X.w);
                    const uint32_t m3p = mkp(X.w, Wp);
                    PA[0] = mm0; PA[1] = X.x; PA[2] = m01; PA[3] = X.y;
                    PA[4] = m12; PA[5] = X.z; PA[6] = m23; PA[7] = X.w;
                    PB[0] = m01; PB[1] = X.y; PB[2] = m12; PB[3] = X.z;
                    PB[4] = m23; PB[5] = X.w; PB[6] = m3p; PB[7] = Wp;
                } else {
                    const uint32_t Em = (w0g > 0) ? ldu(rowp - 2) : 0u;
                    const uint4 Xa = *(const uint4*)rowp;           // D0..D3
                    const uint4 Xb = *(const uint4*)(rowp + 8);     // D4..D7
                    PA[0] = mkp(Em,   Xa.x); PA[1] = mkp(Xa.x, Xa.y);
                    PA[2] = mkp(Xa.y, Xa.z); PA[3] = mkp(Xa.z, Xa.w);
                    PA[4] = mkp(Xa.w, Xb.x); PA[5] = mkp(Xb.x, Xb.y);
                    PA[6] = mkp(Xb.y, Xb.z); PA[7] = mkp(Xb.z, Xb.w);
                    PB[0] = Xa.x; PB[1] = Xa.y; PB[2] = Xa.z; PB[3] = Xa.w;
                    PB[4] = Xb.x; PB[5] = Xb.y; PB[6] = Xb.z; PB[7] = Xb.w;
                }
            } else {  // W8 == 4, S == 2
                const uint32_t E0 = (w0g > 0) ? ldu(rowp - 2) : 0u;
                const uint32_t E1 = ldu(rowp);
                const uint32_t E2 = ldu(rowp + 2);
                const uint32_t E3 = ldu(rowp + 4);
                const uint32_t E4 = ldu(rowp + 6);
                PA[0] = mkp(E0, E1); PA[1] = mkp(E1, E2);
                PA[2] = mkp(E2, E3); PA[3] = mkp(E3, E4);
                PB[0] = E1; PB[1] = E2; PB[2] = E3; PB[3] = E4;
            }
#pragma unroll
            for (int dl = 0; dl < DT; ++dl) {
                const int kd = p - S * dl;             // folds after unroll
                if (kd < 0 || kd > 2) continue;
#pragma unroll
                for (int hh = 0; hh < 4; ++hh) {
                    const int kh = r - S * hh;         // folds after unroll
                    if (kh < 0 || kh > 2) continue;
                    const int t = kd * 3 + kh;
#pragma unroll
                    for (int k = 0; k < W8; ++k)
                        acc[dl][hh][k] = FDOT2(H2(PB[k]), KB[t],
                                         FDOT2(H2(PA[k]), KA[t],
                                               acc[dl][hh][k]));
                }
            }
        };

        const bool dInt = (S * d0 - 1 >= 0) && (S * d0 - 1 + NP - 1 < DIN);
        const bool hInt = (h0t * S - 1 >= 0) && (h0t * S - 1 + 3 * S + 2 < HIN);
        if (dInt && hInt) {
#pragma unroll
            for (int p = 0; p < NP; ++p) {
                const u16* pl = plane0 + (size_t)(S * d0 - 1 + p) * HIN * WIN;
#pragma unroll
                for (int r = 0; r < 3 * S + 3; ++r) row_body(p, r, pl);
            }
        } else {
#pragma unroll
            for (int p = 0; p < NP; ++p) {
                const int din = S * d0 - 1 + p;
                if (din < 0 || din >= DIN) continue;
                const u16* pl = plane0 + (size_t)din * HIN * WIN;
#pragma unroll
                for (int r = 0; r < 3 * S + 3; ++r) {
                    const int hin = h0t * S - 1 + r;
                    if (hin < 0 || hin >= HIN) continue;
                    row_body(p, r, pl);
                }
            }
        }

        const float bia = sDB[ci];
#pragma unroll
        for (int dl = 0; dl < DT; ++dl) {
#pragma unroll
            for (int hh = 0; hh < 4; ++hh) {
                const int h = hh2 * 4 + hh;
#pragma unroll
                for (int k = 0; k < W8; ++k) {
                    const float t = acc[dl][hh][k] + bia;
                    sT[((dl * HT + h) * 48 + wg * W8 + k) * CINP + ci] =
                        f2h(fmaxf(t, 0.1f * t));
                }
            }
        }
    }
    __syncthreads();

    // ---------------- phase 2: pointwise via f16 MFMA ----------------
    constexpr int NT = (COUT + 15) / 16;   // co tiles
    constexpr int KH = (CIN + 31) / 32;    // K=32 chunks
    constexpr int MTW = DT * HT * 3 / 4;   // M-tiles per wave
    const int lane = tid & 63, wave = tid >> 6;
    const int m15 = lane & 15, q = lane >> 4;

    half8_t bf[NT][KH];
    float   pb[NT];
#pragma unroll
    for (int nt = 0; nt < NT; ++nt) {
        const int co = nt * 16 + m15;
        pb[nt] = (co < COUT) ? pw_b[co] : 0.f;
#pragma unroll
        for (int kh = 0; kh < KH; ++kh) {
            union { half8_t v; f16_t e[8]; } u;
#pragma unroll
            for (int j = 0; j < 8; ++j) {
                const int ci = kh * 32 + q * 8 + j;
                u.e[j] = (co < COUT && ci < CIN)
                         ? (f16_t)pw_w[co * CIN + ci] : (f16_t)0.f;
            }
            bf[nt][kh] = u.v;
        }
    }

    const size_t planeSz = (size_t)DO * HO * WO;
    for (int mt = wave * MTW; mt < (wave + 1) * MTW; ++mt) {
        const int dl  = mt / (HT * 3);
        const int rem = mt - dl * (HT * 3);
        const int hh  = rem / 3;
        const int w0  = (rem - hh * 3) * 16;
        if (d0 + dl >= DO) continue;           // tail guard

        const int pos0 = (dl * HT + hh) * 48 + w0 + m15;
        const u16* ap = &sT[(size_t)pos0 * CINP];
        union { uint32_t u[4]; half8_t v; } af[KH];
#pragma unroll
        for (int kh = 0; kh < KH; ++kh) {
            const int ci0 = kh * 32 + q * 8;
            af[kh].u[0] = (ci0     < CIN) ? ldu(ap + ci0)     : 0u;
            af[kh].u[1] = (ci0 + 2 < CIN) ? ldu(ap + ci0 + 2) : 0u;
            af[kh].u[2] = (ci0 + 4 < CIN) ? ldu(ap + ci0 + 4) : 0u;
            af[kh].u[3] = (ci0 + 6 < CIN) ? ldu(ap + ci0 + 6) : 0u;
        }
#pragma unroll
        for (int nt = 0; nt < NT; ++nt) {
            f32x4 acc;
            acc.x = 0.f; acc.y = 0.f; acc.z = 0.f; acc.w = 0.f;
#pragma unroll
            for (int kh = 0; kh < KH; ++kh)
                acc = __builtin_amdgcn_mfma_f32_16x16x32_f16(
                          af[kh].v, bf[nt][kh], acc, 0, 0, 0);
            const int co = nt * 16 + m15;
            if (co < COUT) {
                const float bias = pb[nt];
                TOUT* yp = y + (size_t)b * COUT * planeSz + (size_t)co * planeSz
                             + (size_t)(d0 + dl) * HO * WO
                             + (size_t)(h0 + hh) * WO + wbase + w0 + q * 4;
                float s0 = acc.x + bias, s1 = acc.y + bias;
                float s2 = acc.z + bias, s3 = acc.w + bias;
                s0 = fmaxf(s0, 0.1f * s0); s1 = fmaxf(s1, 0.1f * s1);
                s2 = fmaxf(s2, 0.1f * s2); s3 = fmaxf(s3, 0.1f * s3);
                if constexpr (sizeof(TOUT) == 4) {
                    float4 o; o.x = s0; o.y = s1; o.z = s2; o.w = s3;
                    *(float4*)yp = o;
                } else {
                    ushort4 o;
                    o.x = f2h(s0); o.y = f2h(s1); o.z = f2h(s2); o.w = f2h(s3);
                    *(ushort4*)yp = o;
                }
            }
        }
    }
}

// ---------------------------------------------------------------------------
extern "C" void kernel_launch(void* const* d_in, const int* in_sizes, int n_in,
                              void* d_out, int out_size, void* d_ws, size_t ws_size,
                              hipStream_t stream) {
    const float* rgb  = (const float*)d_in[0];
    const float* dep  = (const float*)d_in[1];
    const float* dw1w = (const float*)d_in[2];
    const float* dw1b = (const float*)d_in[3];
    const float* pw1w = (const float*)d_in[4];
    const float* pw1b = (const float*)d_in[5];
    const float* dw2w = (const float*)d_in[6];
    const float* dw2b = (const float*)d_in[7];
    const float* pw2w = (const float*)d_in[8];
    const float* pw2b = (const float*)d_in[9];
    const float* dw3w = (const float*)d_in[10];
    const float* dw3b = (const float*)d_in[11];
    const float* pw3w = (const float*)d_in[12];
    const float* pw3b = (const float*)d_in[13];
    const float* dw4w = (const float*)d_in[14];
    const float* dw4b = (const float*)d_in[15];
    const float* pw4w = (const float*)d_in[16];
    const float* pw4b = (const float*)d_in[17];

    const size_t HALF = 78643200;
    u16* corrO = (u16*)d_ws;
    u16* rgbT  = (u16*)((char*)d_ws + HALF);
    u16* depT  = (u16*)((char*)d_ws + HALF + 12582912);
    u16* b1o   = (u16*)((char*)d_ws + HALF);   // rgbT/depT dead by then
    u16* b2o   = (u16*)d_ws;                   // corrO dead by then
    u16* b3o   = (u16*)((char*)d_ws + HALF);   // b1o dead by then
    float* outp = (float*)d_out;

    transpose_f16<<<dim3(512, 2), 256, 0, stream>>>(rgb, dep, rgbT, depT);

    corr_mfma<<<dim3(5, 64, 8), 256, 0, stream>>>(rgbT, depT, corrO);

    fused_block<20, 20, 1, 2, 8, 20, 64, 192, 20, 64, 192, u16>
        <<<dim3(32, 10, 8), 256, 0, stream>>>(corrO, dw1w, dw1b, pw1w, pw1b, b1o);

    fused_block<20, 40, 2, 2, 4, 20, 64, 192, 10, 32, 96, u16>
        <<<dim3(16, 5, 8), 256, 0, stream>>>(b1o, dw2w, dw2b, pw2w, pw2b, b2o);

    fused_block<40, 40, 1, 2, 4, 10, 32, 96, 10, 32, 96, u16>
        <<<dim3(16, 5, 8), 256, 0, stream>>>(b2o, dw3w, dw3b, pw3w, pw3b, b3o);

    fused_block<40, 80, 2, 1, 4, 10, 32, 96, 5, 16, 48, float>
        <<<dim3(4, 5, 8), 256, 0, stream>>>(b3o, dw4w, dw4b, pw4w, pw4b, outp);
}